// Round 10
// baseline (237.713 us; speedup 1.0000x reference)
//
#include <hip/hip_runtime.h>

typedef __bf16 bf16_t;
typedef __bf16 bf16x4 __attribute__((ext_vector_type(4)));
typedef __bf16 bf16x8 __attribute__((ext_vector_type(8)));
typedef float  f32x4  __attribute__((ext_vector_type(4)));

// B=4, S=1024, D=1024, H=16, HD=64
// MFMA 16x16x32 bf16 layouts (m89/m91):
//   A-frag: row = lane&15, k = (lane>>4)*8 + j
//   B-frag: col = lane&15, k = (lane>>4)*8 + j  (from B^T rows)
//   C/D:    col = lane&15, row = (lane>>4)*4 + reg

__device__ __forceinline__ void gload16(const bf16_t* g, bf16_t* l) {
  __builtin_amdgcn_global_load_lds((const __attribute__((address_space(1))) void*)g,
                                   (__attribute__((address_space(3))) void*)l, 16, 0, 0);
}

// ---------------- fused prep: x fp32->bf16 + content bias + mask (one x read) ----------------
// block = one row (b*1024+s), 256 threads.
__global__ __launch_bounds__(256) void k_prep(const float* __restrict__ x,
                                              const float* __restrict__ Wb,
                                              const float* __restrict__ mask,
                                              bf16_t* __restrict__ xb,
                                              float* __restrict__ cbm) {
  const int row = blockIdx.x;
  const int t = threadIdx.x;
  __shared__ float xrow[1024];
  __shared__ float ps[16][17];

  const float4 v = *reinterpret_cast<const float4*>(x + (size_t)row * 1024 + t * 4);
  *reinterpret_cast<float4*>(xrow + t * 4) = v;
  bf16x4 o = { (bf16_t)v.x, (bf16_t)v.y, (bf16_t)v.z, (bf16_t)v.w };
  *reinterpret_cast<bf16x4*>(xb + (size_t)row * 1024 + t * 4) = o;
  __syncthreads();

  const int h = t & 15, part = t >> 4;  // 16 heads x 16 k-parts of 64
  const float* wb = Wb + (size_t)part * 64 * 16 + h;
  float s = 0.f;
#pragma unroll 8
  for (int i = 0; i < 64; ++i) s += xrow[part * 64 + i] * wb[i * 16];
  ps[part][h] = s;
  __syncthreads();
  if (t < 16) {
    float vv = 0.f;
#pragma unroll
    for (int p = 0; p < 16; ++p) vv += ps[p][t];
    cbm[((size_t)(row >> 10) * 16 + t) * 1024 + (row & 1023)] = vv + mask[row];
  }
}

// ---------------- batched transpose + cvt: WT[n][k] = W[k][n], 4x 1024x1024 ----------------
__global__ __launch_bounds__(256) void k_transpose_cvt4(
    const float* __restrict__ W0, const float* __restrict__ W1,
    const float* __restrict__ W2, const float* __restrict__ W3,
    bf16_t* __restrict__ T0, bf16_t* __restrict__ T1,
    bf16_t* __restrict__ T2, bf16_t* __restrict__ T3) {
  const float* W; bf16_t* WT;
  switch (blockIdx.y) {
    case 0: W = W0; WT = T0; break;
    case 1: W = W1; WT = T1; break;
    case 2: W = W2; WT = T2; break;
    default: W = W3; WT = T3; break;
  }
  __shared__ float t[32][33];
  int bx = blockIdx.x & 31, by = blockIdx.x >> 5;
  int lx = threadIdx.x & 31, ly = threadIdx.x >> 5;  // 32 x 8
#pragma unroll
  for (int i = 0; i < 32; i += 8)
    t[ly + i][lx] = W[(size_t)(by * 32 + ly + i) * 1024 + bx * 32 + lx];
  __syncthreads();
#pragma unroll
  for (int i = 0; i < 32; i += 8)
    WT[(size_t)(bx * 32 + ly + i) * 1024 + by * 32 + lx] = (bf16_t)t[lx][ly + i];
}

// ---------------- 128x128-tile bf16 GEMM, K=1024 (fused QKV, N=3072) ----------------
// nb 0..7 -> Q (*mixing/8, [b,h,s,d]), nb 8..15 -> K ([b,h,s,d]), nb 16..23 -> V^T ([b,h,d,s])
__global__ __launch_bounds__(256) void k_gemm_qkv(const bf16_t* __restrict__ A,
                                                  const bf16_t* __restrict__ BT,
                                                  const float* __restrict__ aux,
                                                  bf16_t* __restrict__ o0,
                                                  bf16_t* __restrict__ o1,
                                                  bf16_t* __restrict__ o2) {
  constexpr int K = 1024;
  const int tid = threadIdx.x;
  const int w = tid >> 6, lane = tid & 63;
  const int r = lane & 15, g = lane >> 4;
  const int swz = (blockIdx.x & 7) * 96 + (blockIdx.x >> 3);  // XCD-contiguous
  const int nb = swz % 24;
  const int mb = swz / 24;

  __shared__ bf16_t As[128 * 32];
  __shared__ bf16_t Bs[128 * 32];

  f32x4 acc[4][4] = {};

  const bf16_t* Ag = A + (size_t)(mb * 128 + w * 32 + (lane >> 2)) * K + (lane & 3) * 8;
  const bf16_t* Bg = BT + (size_t)(nb * 128 + w * 32 + (lane >> 2)) * K + (lane & 3) * 8;
  bf16_t* Asw = As + (w * 32) * 32;
  bf16_t* Bsw = Bs + (w * 32) * 32;

  const int mrow0 = (w >> 1) * 64, ncol0 = (w & 1) * 64;

  for (int k0 = 0; k0 < K; k0 += 32) {
    gload16(Ag + k0, Asw);
    gload16(Ag + 16 * K + k0, Asw + 16 * 32);
    gload16(Bg + k0, Bsw);
    gload16(Bg + 16 * K + k0, Bsw + 16 * 32);
    asm volatile("s_waitcnt vmcnt(0)" ::: "memory");
    __syncthreads();

    bf16x8 av[4], bv[4];
#pragma unroll
    for (int mi = 0; mi < 4; ++mi)
      av[mi] = *reinterpret_cast<const bf16x8*>(As + (mrow0 + mi * 16 + r) * 32 + g * 8);
#pragma unroll
    for (int ni = 0; ni < 4; ++ni)
      bv[ni] = *reinterpret_cast<const bf16x8*>(Bs + (ncol0 + ni * 16 + r) * 32 + g * 8);
#pragma unroll
    for (int mi = 0; mi < 4; ++mi)
#pragma unroll
      for (int ni = 0; ni < 4; ++ni)
        acc[mi][ni] = __builtin_amdgcn_mfma_f32_16x16x32_bf16(av[mi], bv[ni], acc[mi][ni], 0, 0, 0);
    __syncthreads();
  }

  const int row0 = mb * 128 + mrow0;
  const int matk = nb >> 3;
  const int col0 = (nb & 7) * 128 + ncol0;
#pragma unroll
  for (int mi = 0; mi < 4; ++mi)
#pragma unroll
    for (int ni = 0; ni < 4; ++ni)
#pragma unroll
      for (int rr = 0; rr < 4; ++rr) {
        int row = row0 + mi * 16 + g * 4 + rr;
        int col = col0 + ni * 16 + r;
        int h = col >> 6, dd = col & 63;
        size_t bh_ = (size_t)(row >> 10) * 16 + h;
        float v = acc[mi][ni][rr];
        if (matk == 0) {
          v *= aux[col] * 0.125f;  // mixing[h,dd] flat == col; fold 1/sqrt(64)
          o0[(bh_ * 1024 + (row & 1023)) * 64 + dd] = (bf16_t)v;
        } else if (matk == 1) {
          o1[(bh_ * 1024 + (row & 1023)) * 64 + dd] = (bf16_t)v;
        } else {
          o2[(bh_ * 64 + dd) * 1024 + (row & 1023)] = (bf16_t)v;
        }
      }
}

// ---------------- 64x128-tile dense GEMM, K=1024: out = A@Wd^T + bd (fp32, NT) ----------------
__global__ __launch_bounds__(256) void k_gemm_dense(const bf16_t* __restrict__ A,
                                                    const bf16_t* __restrict__ BT,
                                                    const float* __restrict__ bd,
                                                    float* __restrict__ of) {
  constexpr int K = 1024;
  const int tid = threadIdx.x;
  const int w = tid >> 6, lane = tid & 63;
  const int r = lane & 15, g = lane >> 4;
  const int swz = (blockIdx.x & 7) * 64 + (blockIdx.x >> 3);  // XCD-contiguous
  const int nb = swz & 7;
  const int mb = swz >> 3;

  __shared__ bf16_t As[64 * 32];
  __shared__ bf16_t Bs[128 * 32];

  f32x4 acc[2][4] = {};

  const bf16_t* Ag = A + (size_t)(mb * 64 + w * 16 + (lane >> 2)) * K + (lane & 3) * 8;
  const bf16_t* Bg = BT + (size_t)(nb * 128 + w * 32 + (lane >> 2)) * K + (lane & 3) * 8;
  bf16_t* Asw = As + (w * 16) * 32;
  bf16_t* Bsw = Bs + (w * 32) * 32;

  const int wr = w >> 1, wc = w & 1;  // wave -> 32x64 sub-tile
  const int mrow0 = wr * 32, ncol0 = wc * 64;

  for (int k0 = 0; k0 < K; k0 += 32) {
    gload16(Ag + k0, Asw);
    gload16(Bg + k0, Bsw);
    gload16(Bg + 16 * K + k0, Bsw + 16 * 32);
    asm volatile("s_waitcnt vmcnt(0)" ::: "memory");
    __syncthreads();

    bf16x8 av[2], bv[4];
#pragma unroll
    for (int mi = 0; mi < 2; ++mi)
      av[mi] = *reinterpret_cast<const bf16x8*>(As + (mrow0 + mi * 16 + r) * 32 + g * 8);
#pragma unroll
    for (int ni = 0; ni < 4; ++ni)
      bv[ni] = *reinterpret_cast<const bf16x8*>(Bs + (ncol0 + ni * 16 + r) * 32 + g * 8);
#pragma unroll
    for (int mi = 0; mi < 2; ++mi)
#pragma unroll
      for (int ni = 0; ni < 4; ++ni)
        acc[mi][ni] = __builtin_amdgcn_mfma_f32_16x16x32_bf16(av[mi], bv[ni], acc[mi][ni], 0, 0, 0);
    __syncthreads();
  }

  const int row0 = mb * 64 + mrow0, col0 = nb * 128 + ncol0;
#pragma unroll
  for (int mi = 0; mi < 2; ++mi)
#pragma unroll
    for (int ni = 0; ni < 4; ++ni)
#pragma unroll
      for (int rr = 0; rr < 4; ++rr) {
        int row = row0 + mi * 16 + g * 4 + rr;
        int col = col0 + ni * 16 + r;
        __builtin_nontemporal_store(acc[mi][ni][rr] + bd[col], of + (size_t)row * 1024 + col);
      }
}

// ---------------- fused attn v6: q=64 per block, 8 waves (quarter K/V L2 traffic vs q=16) ----------------
// block: one (b,h), 64 q rows, 512 threads / 8 waves; wave w owns keys [w*128,+128).
// Swapped QK^T: lane(r,g) holds keys t*16+g*4+{0..3} for q = qh*16 + r (qh 0..3).
// Each K/V line feeds 4 q-subtiles. ALL acc indices compile-time (rule #20).
// PV: wave w -> (q-half w>>2, d-cols (w&3)*16). P store LAST (no barrier after global stores).
__global__ __launch_bounds__(512, 2) void k_attn_fused(const bf16_t* __restrict__ Qm,
                                                       const bf16_t* __restrict__ Kw,
                                                       const bf16_t* __restrict__ VT,
                                                       const float* __restrict__ cbm,
                                                       float* __restrict__ P,
                                                       bf16_t* __restrict__ aout) {
  const int tid = threadIdx.x;
  const int w = tid >> 6, lane = tid & 63;
  const int r = lane & 15, g = lane >> 4;
  const int swz = (blockIdx.x & 7) * 128 + (blockIdx.x >> 3);  // XCD-contiguous (b,h) groups
  const int qt = swz & 15;   // 16 q-tiles of 64 rows per bh
  const int bh = swz >> 4;
  const int b = bh >> 4, h = bh & 15;
  const int q0 = qt * 64;

  constexpr int PSTR = 1032;  // row stride 2064B = 516 dwords (516%32=4 -> 2-way, free)
  __shared__ float red[2][64][8];     // 4 KB
  __shared__ bf16_t Plds[64 * PSTR];  // 129 KB

  // Q frags (B-operand), 4 q-subtiles: q = q0 + qh*16 + r
  const bf16_t* qb = Qm + ((size_t)bh * 1024 + q0) * 64;
  bf16x8 bq[4][2];
#pragma unroll
  for (int qh = 0; qh < 4; ++qh) {
    bq[qh][0] = *reinterpret_cast<const bf16x8*>(qb + (qh * 16 + r) * 64 + g * 8);
    bq[qh][1] = *reinterpret_cast<const bf16x8*>(qb + (qh * 16 + r) * 64 + 32 + g * 8);
  }

  // phase 1: S^T tiles. A-frag from K rows (key = w*128 + t*16 + r); reused for 4 qh.
  const bf16_t* kb = Kw + ((size_t)bh * 1024 + w * 128) * 64;
  f32x4 acc[8][4];
#pragma unroll
  for (int t = 0; t < 8; ++t) {
    bf16x8 a0 = *reinterpret_cast<const bf16x8*>(kb + (t * 16 + r) * 64 + g * 8);
    bf16x8 a1 = *reinterpret_cast<const bf16x8*>(kb + (t * 16 + r) * 64 + 32 + g * 8);
#pragma unroll
    for (int qh = 0; qh < 4; ++qh) {
      f32x4 c = {0.f, 0.f, 0.f, 0.f};
      c = __builtin_amdgcn_mfma_f32_16x16x32_bf16(a0, bq[qh][0], c, 0, 0, 0);
      c = __builtin_amdgcn_mfma_f32_16x16x32_bf16(a1, bq[qh][1], c, 0, 0, 0);
      acc[t][qh] = c;
    }
  }

  // bias+mask add (same per qh), per-lane max over this wave's 128 keys
  const float* cv = cbm + (size_t)bh * 1024 + w * 128;
  float mx[4] = {-1e30f, -1e30f, -1e30f, -1e30f};
#pragma unroll
  for (int t = 0; t < 8; ++t) {
    f32x4 c = *reinterpret_cast<const f32x4*>(cv + t * 16 + g * 4);
#pragma unroll
    for (int qh = 0; qh < 4; ++qh) {
      acc[t][qh] += c;
#pragma unroll
      for (int rr = 0; rr < 4; ++rr) mx[qh] = fmaxf(mx[qh], acc[t][qh][rr]);
    }
  }
#pragma unroll
  for (int qh = 0; qh < 4; ++qh) {
    mx[qh] = fmaxf(mx[qh], __shfl_xor(mx[qh], 16));
    mx[qh] = fmaxf(mx[qh], __shfl_xor(mx[qh], 32));
  }
  if (lane < 16) {
#pragma unroll
    for (int qh = 0; qh < 4; ++qh) red[0][qh * 16 + r][w] = mx[qh];
  }
  __syncthreads();
  float m[4], sum[4] = {0.f, 0.f, 0.f, 0.f};
#pragma unroll
  for (int qh = 0; qh < 4; ++qh) {
    float v = red[0][qh * 16 + r][0];
#pragma unroll
    for (int ww = 1; ww < 8; ++ww) v = fmaxf(v, red[0][qh * 16 + r][ww]);
    m[qh] = v;
  }
#pragma unroll
  for (int t = 0; t < 8; ++t)
#pragma unroll
    for (int qh = 0; qh < 4; ++qh)
#pragma unroll
      for (int rr = 0; rr < 4; ++rr) {
        float p = __expf(acc[t][qh][rr] - m[qh]);
        acc[t][qh][rr] = p;
        sum[qh] += p;
      }
#pragma unroll
  for (int qh = 0; qh < 4; ++qh) {
    sum[qh] += __shfl_xor(sum[qh], 16);
    sum[qh] += __shfl_xor(sum[qh], 32);
  }
  if (lane < 16) {
#pragma unroll
    for (int qh = 0; qh < 4; ++qh) red[1][qh * 16 + r][w] = sum[qh];
  }
  __syncthreads();
  float l[4];
#pragma unroll
  for (int qh = 0; qh < 4; ++qh) {
    float v = red[1][qh * 16 + r][0];
#pragma unroll
    for (int ww = 1; ww < 8; ++ww) v += red[1][qh * 16 + r][ww];
    l[qh] = 1.f / v;
  }

  // normalized P -> LDS (bf16, rows = q 0..63)
#pragma unroll
  for (int qh = 0; qh < 4; ++qh) {
    bf16_t* pl = Plds + (qh * 16 + r) * PSTR + w * 128;
#pragma unroll
    for (int t = 0; t < 8; ++t) {
      f32x4 pv = acc[t][qh] * l[qh];
      bf16x4 pk = { (bf16_t)pv[0], (bf16_t)pv[1], (bf16_t)pv[2], (bf16_t)pv[3] };
      *reinterpret_cast<bf16x4*>(pl + t * 16 + g * 4) = pk;
    }
  }
  __syncthreads();  // LDS-only waits: no global stores issued yet

  // phase 2: PV. wave w -> q-half qh2 = w>>2 (rows qh2*32..+32), d-cols dc = (w&3)*16.
  const int qh2 = w >> 2, dc = (w & 3) * 16;
  const bf16_t* vb = VT + ((size_t)bh * 64 + dc) * 1024;
  f32x4 oacc0 = {0.f, 0.f, 0.f, 0.f}, oacc1 = {0.f, 0.f, 0.f, 0.f};
#pragma unroll
  for (int kbl = 0; kbl < 32; ++kbl) {
    bf16x8 bv = *reinterpret_cast<const bf16x8*>(vb + (size_t)r * 1024 + kbl * 32 + g * 8);
    bf16x8 av0 = *reinterpret_cast<const bf16x8*>(Plds + (qh2 * 32 + r) * PSTR + kbl * 32 + g * 8);
    bf16x8 av1 = *reinterpret_cast<const bf16x8*>(Plds + (qh2 * 32 + 16 + r) * PSTR + kbl * 32 + g * 8);
    oacc0 = __builtin_amdgcn_mfma_f32_16x16x32_bf16(av0, bv, oacc0, 0, 0, 0);
    oacc1 = __builtin_amdgcn_mfma_f32_16x16x32_bf16(av1, bv, oacc1, 0, 0, 0);
  }
#pragma unroll
  for (int rr = 0; rr < 4; ++rr)
    aout[((size_t)b * 1024 + q0 + qh2 * 32 + g * 4 + rr) * 1024 + h * 64 + dc + r] = (bf16_t)oacc0[rr];
#pragma unroll
  for (int rr = 0; rr < 4; ++rr)
    aout[((size_t)b * 1024 + q0 + qh2 * 32 + 16 + g * 4 + rr) * 1024 + h * 64 + dc + r] = (bf16_t)oacc1[rr];

  // phase 3 (LAST): P fp32 coalesced NT store from Plds. Wave w owns rows [w*8,+8).
  {
    float* pg = P + ((size_t)bh * 1024 + q0) * 1024;
#pragma unroll
    for (int j = 0; j < 8; ++j) {
      const int row = w * 8 + j;
#pragma unroll
      for (int half = 0; half < 2; ++half) {
        const int col = half * 512 + lane * 8;
        bf16x8 v = *reinterpret_cast<const bf16x8*>(Plds + row * PSTR + col);
        f32x4 lo = { (float)v[0], (float)v[1], (float)v[2], (float)v[3] };
        f32x4 hi = { (float)v[4], (float)v[5], (float)v[6], (float)v[7] };
        float* dst = pg + (size_t)row * 1024 + col;
        __builtin_nontemporal_store(lo, reinterpret_cast<f32x4*>(dst));
        __builtin_nontemporal_store(hi, reinterpret_cast<f32x4*>(dst + 4));
      }
    }
  }
}

extern "C" void kernel_launch(void* const* d_in, const int* in_sizes, int n_in,
                              void* d_out, int out_size, void* d_ws, size_t ws_size,
                              hipStream_t stream) {
  const float* x      = (const float*)d_in[0];
  const float* mask   = (const float*)d_in[1];
  const float* Wq     = (const float*)d_in[2];
  const float* Wk     = (const float*)d_in[3];
  const float* Wv     = (const float*)d_in[4];
  const float* Wb     = (const float*)d_in[5];
  const float* mixing = (const float*)d_in[6];
  const float* Wd     = (const float*)d_in[7];
  const float* bd     = (const float*)d_in[8];

  char* ws = (char*)d_ws;
  bf16_t* xb   = (bf16_t*)(ws + 0);         //  8,388,608
  bf16_t* WqT  = (bf16_t*)(ws + 8388608);   //  2,097,152  } contiguous: one
  bf16_t* WkT  = (bf16_t*)(ws + 10485760);  //  2,097,152  } N=3072 B^T for
  bf16_t* WvT  = (bf16_t*)(ws + 12582912);  //  2,097,152  } fused QKV GEMM
  bf16_t* WdT  = (bf16_t*)(ws + 14680064);  //  2,097,152
  bf16_t* Qm   = (bf16_t*)(ws + 16777216);  //  8,388,608  [b,h,s,d] * mixing/8
  bf16_t* Kw   = (bf16_t*)(ws + 25165824);  //  8,388,608  [b,h,s,d]
  bf16_t* VT   = (bf16_t*)(ws + 33554432);  //  8,388,608  [b,h,d,s]
  bf16_t* aout = (bf16_t*)(ws + 41943040);  //  8,388,608  [b,s,(h,hd)]
  float*  cbm  = (float*)(ws + 50331648);   //    262,144  [b,h,s] bias+mask
  if (ws_size < 50593792) return;

  float* outO = (float*)d_out;        // attn_output [4,1024,1024]
  float* outP = outO + 4194304;       // attn_weights [4,16,1024,1024]

  k_prep<<<4096, 256, 0, stream>>>(x, Wb, mask, xb, cbm);
  k_transpose_cvt4<<<dim3(1024, 4), 256, 0, stream>>>(Wq, Wk, Wv, Wd, WqT, WkT, WvT, WdT);
  k_gemm_qkv<<<768, 256, 0, stream>>>(xb, WqT, mixing, Qm, Kw, VT);
  k_attn_fused<<<1024, 512, 0, stream>>>(Qm, Kw, VT, cbm, outP, aout);
  k_gemm_dense<<<512, 256, 0, stream>>>(aout, WdT, bd, outO);
}

// Round 11
// 233.625 us; speedup vs baseline: 1.0175x; 1.0175x over previous
//
#include <hip/hip_runtime.h>

typedef __bf16 bf16_t;
typedef __bf16 bf16x4 __attribute__((ext_vector_type(4)));
typedef __bf16 bf16x8 __attribute__((ext_vector_type(8)));
typedef float  f32x4  __attribute__((ext_vector_type(4)));

// B=4, S=1024, D=1024, H=16, HD=64
// MFMA 16x16x32 bf16 layouts (m89/m91):
//   A-frag: row = lane&15, k = (lane>>4)*8 + j
//   B-frag: col = lane&15, k = (lane>>4)*8 + j  (from B^T rows)
//   C/D:    col = lane&15, row = (lane>>4)*4 + reg

__device__ __forceinline__ void gload16(const bf16_t* g, bf16_t* l) {
  __builtin_amdgcn_global_load_lds((const __attribute__((address_space(1))) void*)g,
                                   (__attribute__((address_space(3))) void*)l, 16, 0, 0);
}

// ---------------- fused prep: x fp32->bf16 + content bias + mask (one x read) ----------------
// block = one row (b*1024+s), 256 threads.
__global__ __launch_bounds__(256) void k_prep(const float* __restrict__ x,
                                              const float* __restrict__ Wb,
                                              const float* __restrict__ mask,
                                              bf16_t* __restrict__ xb,
                                              float* __restrict__ cbm) {
  const int row = blockIdx.x;
  const int t = threadIdx.x;
  __shared__ float xrow[1024];
  __shared__ float ps[16][17];

  const float4 v = *reinterpret_cast<const float4*>(x + (size_t)row * 1024 + t * 4);
  *reinterpret_cast<float4*>(xrow + t * 4) = v;
  bf16x4 o = { (bf16_t)v.x, (bf16_t)v.y, (bf16_t)v.z, (bf16_t)v.w };
  *reinterpret_cast<bf16x4*>(xb + (size_t)row * 1024 + t * 4) = o;
  __syncthreads();

  const int h = t & 15, part = t >> 4;  // 16 heads x 16 k-parts of 64
  const float* wb = Wb + (size_t)part * 64 * 16 + h;
  float s = 0.f;
#pragma unroll 8
  for (int i = 0; i < 64; ++i) s += xrow[part * 64 + i] * wb[i * 16];
  ps[part][h] = s;
  __syncthreads();
  if (t < 16) {
    float vv = 0.f;
#pragma unroll
    for (int p = 0; p < 16; ++p) vv += ps[p][t];
    cbm[((size_t)(row >> 10) * 16 + t) * 1024 + (row & 1023)] = vv + mask[row];
  }
}

// ---------------- batched transpose + cvt: WT[n][k] = W[k][n], 4x 1024x1024 ----------------
__global__ __launch_bounds__(256) void k_transpose_cvt4(
    const float* __restrict__ W0, const float* __restrict__ W1,
    const float* __restrict__ W2, const float* __restrict__ W3,
    bf16_t* __restrict__ T0, bf16_t* __restrict__ T1,
    bf16_t* __restrict__ T2, bf16_t* __restrict__ T3) {
  const float* W; bf16_t* WT;
  switch (blockIdx.y) {
    case 0: W = W0; WT = T0; break;
    case 1: W = W1; WT = T1; break;
    case 2: W = W2; WT = T2; break;
    default: W = W3; WT = T3; break;
  }
  __shared__ float t[32][33];
  int bx = blockIdx.x & 31, by = blockIdx.x >> 5;
  int lx = threadIdx.x & 31, ly = threadIdx.x >> 5;  // 32 x 8
#pragma unroll
  for (int i = 0; i < 32; i += 8)
    t[ly + i][lx] = W[(size_t)(by * 32 + ly + i) * 1024 + bx * 32 + lx];
  __syncthreads();
#pragma unroll
  for (int i = 0; i < 32; i += 8)
    WT[(size_t)(bx * 32 + ly + i) * 1024 + by * 32 + lx] = (bf16_t)t[lx][ly + i];
}

// ---------------- 128x128-tile bf16 GEMM, K=1024 (fused QKV, N=3072) ----------------
// nb 0..7 -> Q (*mixing/8, [b,h,s,d]), nb 8..15 -> K ([b,h,s,d]), nb 16..23 -> V^T ([b,h,d,s])
__global__ __launch_bounds__(256) void k_gemm_qkv(const bf16_t* __restrict__ A,
                                                  const bf16_t* __restrict__ BT,
                                                  const float* __restrict__ aux,
                                                  bf16_t* __restrict__ o0,
                                                  bf16_t* __restrict__ o1,
                                                  bf16_t* __restrict__ o2) {
  constexpr int K = 1024;
  const int tid = threadIdx.x;
  const int w = tid >> 6, lane = tid & 63;
  const int r = lane & 15, g = lane >> 4;
  const int swz = (blockIdx.x & 7) * 96 + (blockIdx.x >> 3);  // XCD-contiguous
  const int nb = swz % 24;
  const int mb = swz / 24;

  __shared__ bf16_t As[128 * 32];
  __shared__ bf16_t Bs[128 * 32];

  f32x4 acc[4][4] = {};

  const bf16_t* Ag = A + (size_t)(mb * 128 + w * 32 + (lane >> 2)) * K + (lane & 3) * 8;
  const bf16_t* Bg = BT + (size_t)(nb * 128 + w * 32 + (lane >> 2)) * K + (lane & 3) * 8;
  bf16_t* Asw = As + (w * 32) * 32;
  bf16_t* Bsw = Bs + (w * 32) * 32;

  const int mrow0 = (w >> 1) * 64, ncol0 = (w & 1) * 64;

  for (int k0 = 0; k0 < K; k0 += 32) {
    gload16(Ag + k0, Asw);
    gload16(Ag + 16 * K + k0, Asw + 16 * 32);
    gload16(Bg + k0, Bsw);
    gload16(Bg + 16 * K + k0, Bsw + 16 * 32);
    asm volatile("s_waitcnt vmcnt(0)" ::: "memory");
    __syncthreads();

    bf16x8 av[4], bv[4];
#pragma unroll
    for (int mi = 0; mi < 4; ++mi)
      av[mi] = *reinterpret_cast<const bf16x8*>(As + (mrow0 + mi * 16 + r) * 32 + g * 8);
#pragma unroll
    for (int ni = 0; ni < 4; ++ni)
      bv[ni] = *reinterpret_cast<const bf16x8*>(Bs + (ncol0 + ni * 16 + r) * 32 + g * 8);
#pragma unroll
    for (int mi = 0; mi < 4; ++mi)
#pragma unroll
      for (int ni = 0; ni < 4; ++ni)
        acc[mi][ni] = __builtin_amdgcn_mfma_f32_16x16x32_bf16(av[mi], bv[ni], acc[mi][ni], 0, 0, 0);
    __syncthreads();
  }

  const int row0 = mb * 128 + mrow0;
  const int matk = nb >> 3;
  const int col0 = (nb & 7) * 128 + ncol0;
#pragma unroll
  for (int mi = 0; mi < 4; ++mi)
#pragma unroll
    for (int ni = 0; ni < 4; ++ni)
#pragma unroll
      for (int rr = 0; rr < 4; ++rr) {
        int row = row0 + mi * 16 + g * 4 + rr;
        int col = col0 + ni * 16 + r;
        int h = col >> 6, dd = col & 63;
        size_t bh_ = (size_t)(row >> 10) * 16 + h;
        float v = acc[mi][ni][rr];
        if (matk == 0) {
          v *= aux[col] * 0.125f;  // mixing[h,dd] flat == col; fold 1/sqrt(64)
          o0[(bh_ * 1024 + (row & 1023)) * 64 + dd] = (bf16_t)v;
        } else if (matk == 1) {
          o1[(bh_ * 1024 + (row & 1023)) * 64 + dd] = (bf16_t)v;
        } else {
          o2[(bh_ * 64 + dd) * 1024 + (row & 1023)] = (bf16_t)v;
        }
      }
}

// ---------------- 64x128-tile dense GEMM, K=1024: out = A@Wd^T + bd (fp32, NT) ----------------
__global__ __launch_bounds__(256) void k_gemm_dense(const bf16_t* __restrict__ A,
                                                    const bf16_t* __restrict__ BT,
                                                    const float* __restrict__ bd,
                                                    float* __restrict__ of) {
  constexpr int K = 1024;
  const int tid = threadIdx.x;
  const int w = tid >> 6, lane = tid & 63;
  const int r = lane & 15, g = lane >> 4;
  const int swz = (blockIdx.x & 7) * 64 + (blockIdx.x >> 3);  // XCD-contiguous
  const int nb = swz & 7;
  const int mb = swz >> 3;

  __shared__ bf16_t As[64 * 32];
  __shared__ bf16_t Bs[128 * 32];

  f32x4 acc[2][4] = {};

  const bf16_t* Ag = A + (size_t)(mb * 64 + w * 16 + (lane >> 2)) * K + (lane & 3) * 8;
  const bf16_t* Bg = BT + (size_t)(nb * 128 + w * 32 + (lane >> 2)) * K + (lane & 3) * 8;
  bf16_t* Asw = As + (w * 16) * 32;
  bf16_t* Bsw = Bs + (w * 32) * 32;

  const int wr = w >> 1, wc = w & 1;  // wave -> 32x64 sub-tile
  const int mrow0 = wr * 32, ncol0 = wc * 64;

  for (int k0 = 0; k0 < K; k0 += 32) {
    gload16(Ag + k0, Asw);
    gload16(Bg + k0, Bsw);
    gload16(Bg + 16 * K + k0, Bsw + 16 * 32);
    asm volatile("s_waitcnt vmcnt(0)" ::: "memory");
    __syncthreads();

    bf16x8 av[2], bv[4];
#pragma unroll
    for (int mi = 0; mi < 2; ++mi)
      av[mi] = *reinterpret_cast<const bf16x8*>(As + (mrow0 + mi * 16 + r) * 32 + g * 8);
#pragma unroll
    for (int ni = 0; ni < 4; ++ni)
      bv[ni] = *reinterpret_cast<const bf16x8*>(Bs + (ncol0 + ni * 16 + r) * 32 + g * 8);
#pragma unroll
    for (int mi = 0; mi < 2; ++mi)
#pragma unroll
      for (int ni = 0; ni < 4; ++ni)
        acc[mi][ni] = __builtin_amdgcn_mfma_f32_16x16x32_bf16(av[mi], bv[ni], acc[mi][ni], 0, 0, 0);
    __syncthreads();
  }

  const int row0 = mb * 64 + mrow0, col0 = nb * 128 + ncol0;
#pragma unroll
  for (int mi = 0; mi < 2; ++mi)
#pragma unroll
    for (int ni = 0; ni < 4; ++ni)
#pragma unroll
      for (int rr = 0; rr < 4; ++rr) {
        int row = row0 + mi * 16 + g * 4 + rr;
        int col = col0 + ni * 16 + r;
        __builtin_nontemporal_store(acc[mi][ni][rr] + bd[col], of + (size_t)row * 1024 + col);
      }
}

// ---------------- fused attn v7: q=32, 512 threads / 8 waves -> 16 waves/CU ----------------
// R10 lesson: q=64 (1 block/CU) regressed -- occupancy, not traffic, is the binding
// constraint past q=32. This keeps R9's traffic (536MB K/V) and LDS (66KB -> 2 blocks/CU)
// but splits work over 8 waves: wave w owns keys [w*128,+128), acc 64 VGPR (vs 128).
// __launch_bounds__(512,4) caps VGPR at 128 so 2 blocks (16 waves, 4/SIMD) fit per CU.
// ALL acc indices compile-time (rule #20). P store LAST (no barrier after global stores).
__global__ __launch_bounds__(512, 4) void k_attn_fused(const bf16_t* __restrict__ Qm,
                                                       const bf16_t* __restrict__ Kw,
                                                       const bf16_t* __restrict__ VT,
                                                       const float* __restrict__ cbm,
                                                       float* __restrict__ P,
                                                       bf16_t* __restrict__ aout) {
  const int tid = threadIdx.x;
  const int w = tid >> 6, lane = tid & 63;
  const int r = lane & 15, g = lane >> 4;
  const int swz = (blockIdx.x & 7) * 256 + (blockIdx.x >> 3);  // XCD-contiguous (b,h) groups
  const int qt = swz & 31;   // 32 q-tiles of 32 rows per bh
  const int bh = swz >> 5;
  const int b = bh >> 4, h = bh & 15;
  const int q0 = qt * 32;

  constexpr int PSTR = 1032;  // row stride 2064B = 516 dwords (516%32=4 -> 2-way, free)
  __shared__ float red[2][32][8];     // 2 KB
  __shared__ bf16_t Plds[32 * PSTR];  // 64.5 KB

  // Q frags (B-operand), 2 q-subtiles: q = q0 + qh*16 + r
  const bf16_t* qb = Qm + ((size_t)bh * 1024 + q0) * 64;
  bf16x8 bq00 = *reinterpret_cast<const bf16x8*>(qb + r * 64 + g * 8);
  bf16x8 bq01 = *reinterpret_cast<const bf16x8*>(qb + r * 64 + 32 + g * 8);
  bf16x8 bq10 = *reinterpret_cast<const bf16x8*>(qb + (16 + r) * 64 + g * 8);
  bf16x8 bq11 = *reinterpret_cast<const bf16x8*>(qb + (16 + r) * 64 + 32 + g * 8);

  // phase 1: S^T tiles. A-frag from K rows (key = w*128 + t*16 + r); reused for both qh.
  const bf16_t* kb = Kw + ((size_t)bh * 1024 + w * 128) * 64;
  f32x4 acc[8][2];
#pragma unroll
  for (int t = 0; t < 8; ++t) {
    bf16x8 a0 = *reinterpret_cast<const bf16x8*>(kb + (t * 16 + r) * 64 + g * 8);
    bf16x8 a1 = *reinterpret_cast<const bf16x8*>(kb + (t * 16 + r) * 64 + 32 + g * 8);
    f32x4 c0 = {0.f, 0.f, 0.f, 0.f};
    c0 = __builtin_amdgcn_mfma_f32_16x16x32_bf16(a0, bq00, c0, 0, 0, 0);
    c0 = __builtin_amdgcn_mfma_f32_16x16x32_bf16(a1, bq01, c0, 0, 0, 0);
    acc[t][0] = c0;
    f32x4 c1 = {0.f, 0.f, 0.f, 0.f};
    c1 = __builtin_amdgcn_mfma_f32_16x16x32_bf16(a0, bq10, c1, 0, 0, 0);
    c1 = __builtin_amdgcn_mfma_f32_16x16x32_bf16(a1, bq11, c1, 0, 0, 0);
    acc[t][1] = c1;
  }

  // bias+mask add (same per qh), per-lane max over this wave's 128 keys
  const float* cv = cbm + (size_t)bh * 1024 + w * 128;
  float mx[2] = {-1e30f, -1e30f};
#pragma unroll
  for (int t = 0; t < 8; ++t) {
    f32x4 c = *reinterpret_cast<const f32x4*>(cv + t * 16 + g * 4);
#pragma unroll
    for (int qh = 0; qh < 2; ++qh) {
      acc[t][qh] += c;
#pragma unroll
      for (int rr = 0; rr < 4; ++rr) mx[qh] = fmaxf(mx[qh], acc[t][qh][rr]);
    }
  }
#pragma unroll
  for (int qh = 0; qh < 2; ++qh) {
    mx[qh] = fmaxf(mx[qh], __shfl_xor(mx[qh], 16));
    mx[qh] = fmaxf(mx[qh], __shfl_xor(mx[qh], 32));
  }
  if (lane < 16) { red[0][r][w] = mx[0]; red[0][16 + r][w] = mx[1]; }
  __syncthreads();
  float m[2], sum[2] = {0.f, 0.f};
#pragma unroll
  for (int qh = 0; qh < 2; ++qh) {
    float v = red[0][qh * 16 + r][0];
#pragma unroll
    for (int ww = 1; ww < 8; ++ww) v = fmaxf(v, red[0][qh * 16 + r][ww]);
    m[qh] = v;
  }
#pragma unroll
  for (int t = 0; t < 8; ++t)
#pragma unroll
    for (int qh = 0; qh < 2; ++qh)
#pragma unroll
      for (int rr = 0; rr < 4; ++rr) {
        float p = __expf(acc[t][qh][rr] - m[qh]);
        acc[t][qh][rr] = p;
        sum[qh] += p;
      }
#pragma unroll
  for (int qh = 0; qh < 2; ++qh) {
    sum[qh] += __shfl_xor(sum[qh], 16);
    sum[qh] += __shfl_xor(sum[qh], 32);
  }
  if (lane < 16) { red[1][r][w] = sum[0]; red[1][16 + r][w] = sum[1]; }
  __syncthreads();
  float l[2];
#pragma unroll
  for (int qh = 0; qh < 2; ++qh) {
    float v = red[1][qh * 16 + r][0];
#pragma unroll
    for (int ww = 1; ww < 8; ++ww) v += red[1][qh * 16 + r][ww];
    l[qh] = 1.f / v;
  }

  // normalized P -> LDS (bf16, rows = q 0..31)
#pragma unroll
  for (int qh = 0; qh < 2; ++qh) {
    bf16_t* pl = Plds + (qh * 16 + r) * PSTR + w * 128;
#pragma unroll
    for (int t = 0; t < 8; ++t) {
      f32x4 pv = acc[t][qh] * l[qh];
      bf16x4 pk = { (bf16_t)pv[0], (bf16_t)pv[1], (bf16_t)pv[2], (bf16_t)pv[3] };
      *reinterpret_cast<bf16x4*>(pl + t * 16 + g * 4) = pk;
    }
  }
  __syncthreads();  // LDS-only waits: no global stores issued yet

  // phase 2: PV. wave w -> q-half qh2 = w>>2 (16 rows), d-cols dc = (w&3)*16.
  const int qh2 = w >> 2, dc = (w & 3) * 16;
  const bf16_t* vb = VT + ((size_t)bh * 64 + dc) * 1024;
  f32x4 oacc = {0.f, 0.f, 0.f, 0.f};
#pragma unroll
  for (int kbl = 0; kbl < 32; ++kbl) {
    bf16x8 bv = *reinterpret_cast<const bf16x8*>(vb + (size_t)r * 1024 + kbl * 32 + g * 8);
    bf16x8 av = *reinterpret_cast<const bf16x8*>(Plds + (qh2 * 16 + r) * PSTR + kbl * 32 + g * 8);
    oacc = __builtin_amdgcn_mfma_f32_16x16x32_bf16(av, bv, oacc, 0, 0, 0);
  }
#pragma unroll
  for (int rr = 0; rr < 4; ++rr)
    aout[((size_t)b * 1024 + q0 + qh2 * 16 + g * 4 + rr) * 1024 + h * 64 + dc + r] = (bf16_t)oacc[rr];

  // phase 3 (LAST): P fp32 coalesced NT store from Plds. Wave w owns rows [w*4,+4).
  {
    float* pg = P + ((size_t)bh * 1024 + q0) * 1024;
#pragma unroll
    for (int j = 0; j < 4; ++j) {
      const int row = w * 4 + j;
#pragma unroll
      for (int half = 0; half < 2; ++half) {
        const int col = half * 512 + lane * 8;
        bf16x8 v = *reinterpret_cast<const bf16x8*>(Plds + row * PSTR + col);
        f32x4 lo = { (float)v[0], (float)v[1], (float)v[2], (float)v[3] };
        f32x4 hi = { (float)v[4], (float)v[5], (float)v[6], (float)v[7] };
        float* dst = pg + (size_t)row * 1024 + col;
        __builtin_nontemporal_store(lo, reinterpret_cast<f32x4*>(dst));
        __builtin_nontemporal_store(hi, reinterpret_cast<f32x4*>(dst + 4));
      }
    }
  }
}

extern "C" void kernel_launch(void* const* d_in, const int* in_sizes, int n_in,
                              void* d_out, int out_size, void* d_ws, size_t ws_size,
                              hipStream_t stream) {
  const float* x      = (const float*)d_in[0];
  const float* mask   = (const float*)d_in[1];
  const float* Wq     = (const float*)d_in[2];
  const float* Wk     = (const float*)d_in[3];
  const float* Wv     = (const float*)d_in[4];
  const float* Wb     = (const float*)d_in[5];
  const float* mixing = (const float*)d_in[6];
  const float* Wd     = (const float*)d_in[7];
  const float* bd     = (const float*)d_in[8];

  char* ws = (char*)d_ws;
  bf16_t* xb   = (bf16_t*)(ws + 0);         //  8,388,608
  bf16_t* WqT  = (bf16_t*)(ws + 8388608);   //  2,097,152  } contiguous: one
  bf16_t* WkT  = (bf16_t*)(ws + 10485760);  //  2,097,152  } N=3072 B^T for
  bf16_t* WvT  = (bf16_t*)(ws + 12582912);  //  2,097,152  } fused QKV GEMM
  bf16_t* WdT  = (bf16_t*)(ws + 14680064);  //  2,097,152
  bf16_t* Qm   = (bf16_t*)(ws + 16777216);  //  8,388,608  [b,h,s,d] * mixing/8
  bf16_t* Kw   = (bf16_t*)(ws + 25165824);  //  8,388,608  [b,h,s,d]
  bf16_t* VT   = (bf16_t*)(ws + 33554432);  //  8,388,608  [b,h,d,s]
  bf16_t* aout = (bf16_t*)(ws + 41943040);  //  8,388,608  [b,s,(h,hd)]
  float*  cbm  = (float*)(ws + 50331648);   //    262,144  [b,h,s] bias+mask
  if (ws_size < 50593792) return;

  float* outO = (float*)d_out;        // attn_output [4,1024,1024]
  float* outP = outO + 4194304;       // attn_weights [4,16,1024,1024]

  k_prep<<<4096, 256, 0, stream>>>(x, Wb, mask, xb, cbm);
  k_transpose_cvt4<<<dim3(1024, 4), 256, 0, stream>>>(Wq, Wk, Wv, Wd, WqT, WkT, WvT, WdT);
  k_gemm_qkv<<<768, 256, 0, stream>>>(xb, WqT, mixing, Qm, Kw, VT);
  k_attn_fused<<<2048, 512, 0, stream>>>(Qm, Kw, VT, cbm, outP, aout);
  k_gemm_dense<<<512, 256, 0, stream>>>(aout, WdT, bd, outO);
}

// Round 12
// 201.900 us; speedup vs baseline: 1.1774x; 1.1571x over previous
//
#include <hip/hip_runtime.h>

typedef __bf16 bf16_t;
typedef __bf16 bf16x4 __attribute__((ext_vector_type(4)));
typedef __bf16 bf16x8 __attribute__((ext_vector_type(8)));
typedef float  f32x4  __attribute__((ext_vector_type(4)));

// B=4, S=1024, D=1024, H=16, HD=64
// MFMA 16x16x32 bf16 layouts (m89/m91):
//   A-frag: row = lane&15, k = (lane>>4)*8 + j
//   B-frag: col = lane&15, k = (lane>>4)*8 + j  (from B^T rows)
//   C/D:    col = lane&15, row = (lane>>4)*4 + reg
//
// Attn-friendly permuted layouts (R12): halve cache-line touches per frag load.
//   K'[bh][t=key>>4][half=d>>5][g=(d>>3)&3][r=key&15][j=d&7]
//     -> a0/a1 load = 64 lanes reading one dense 1KB window (8 lines, was 16)
//   V'[bh][kbl=k>>5][gk=(k>>3)&3][d][j=k&7]
//     -> bv load = 4 aligned 256B chunks (8 lines, was 16)

__device__ __forceinline__ void gload16(const bf16_t* g, bf16_t* l) {
  __builtin_amdgcn_global_load_lds((const __attribute__((address_space(1))) void*)g,
                                   (__attribute__((address_space(3))) void*)l, 16, 0, 0);
}

// ---------------- fused prep: x fp32->bf16 + content bias + mask (one x read) ----------------
__global__ __launch_bounds__(256) void k_prep(const float* __restrict__ x,
                                              const float* __restrict__ Wb,
                                              const float* __restrict__ mask,
                                              bf16_t* __restrict__ xb,
                                              float* __restrict__ cbm) {
  const int row = blockIdx.x;
  const int t = threadIdx.x;
  __shared__ float xrow[1024];
  __shared__ float ps[16][17];

  const float4 v = *reinterpret_cast<const float4*>(x + (size_t)row * 1024 + t * 4);
  *reinterpret_cast<float4*>(xrow + t * 4) = v;
  bf16x4 o = { (bf16_t)v.x, (bf16_t)v.y, (bf16_t)v.z, (bf16_t)v.w };
  *reinterpret_cast<bf16x4*>(xb + (size_t)row * 1024 + t * 4) = o;
  __syncthreads();

  const int h = t & 15, part = t >> 4;
  const float* wb = Wb + (size_t)part * 64 * 16 + h;
  float s = 0.f;
#pragma unroll 8
  for (int i = 0; i < 64; ++i) s += xrow[part * 64 + i] * wb[i * 16];
  ps[part][h] = s;
  __syncthreads();
  if (t < 16) {
    float vv = 0.f;
#pragma unroll
    for (int p = 0; p < 16; ++p) vv += ps[p][t];
    cbm[((size_t)(row >> 10) * 16 + t) * 1024 + (row & 1023)] = vv + mask[row];
  }
}

// ---------------- batched transpose + cvt: WT[n][k] = W[k][n], 4x 1024x1024 ----------------
__global__ __launch_bounds__(256) void k_transpose_cvt4(
    const float* __restrict__ W0, const float* __restrict__ W1,
    const float* __restrict__ W2, const float* __restrict__ W3,
    bf16_t* __restrict__ T0, bf16_t* __restrict__ T1,
    bf16_t* __restrict__ T2, bf16_t* __restrict__ T3) {
  const float* W; bf16_t* WT;
  switch (blockIdx.y) {
    case 0: W = W0; WT = T0; break;
    case 1: W = W1; WT = T1; break;
    case 2: W = W2; WT = T2; break;
    default: W = W3; WT = T3; break;
  }
  __shared__ float t[32][33];
  int bx = blockIdx.x & 31, by = blockIdx.x >> 5;
  int lx = threadIdx.x & 31, ly = threadIdx.x >> 5;
#pragma unroll
  for (int i = 0; i < 32; i += 8)
    t[ly + i][lx] = W[(size_t)(by * 32 + ly + i) * 1024 + bx * 32 + lx];
  __syncthreads();
#pragma unroll
  for (int i = 0; i < 32; i += 8)
    WT[(size_t)(bx * 32 + ly + i) * 1024 + by * 32 + lx] = (bf16_t)t[lx][ly + i];
}

// ---------------- 128x128-tile bf16 GEMM, K=1024 (fused QKV, N=3072) ----------------
// nb 0..7 -> Q (*mixing/8, [b,h,s,d]); nb 8..15 -> K' permuted; nb 16..23 -> V' permuted.
__global__ __launch_bounds__(256) void k_gemm_qkv(const bf16_t* __restrict__ A,
                                                  const bf16_t* __restrict__ BT,
                                                  const float* __restrict__ aux,
                                                  bf16_t* __restrict__ o0,
                                                  bf16_t* __restrict__ o1,
                                                  bf16_t* __restrict__ o2) {
  constexpr int K = 1024;
  const int tid = threadIdx.x;
  const int w = tid >> 6, lane = tid & 63;
  const int r = lane & 15, g = lane >> 4;
  const int swz = (blockIdx.x & 7) * 96 + (blockIdx.x >> 3);  // XCD-contiguous
  const int nb = swz % 24;
  const int mb = swz / 24;

  __shared__ bf16_t As[128 * 32];
  __shared__ bf16_t Bs[128 * 32];

  f32x4 acc[4][4] = {};

  const bf16_t* Ag = A + (size_t)(mb * 128 + w * 32 + (lane >> 2)) * K + (lane & 3) * 8;
  const bf16_t* Bg = BT + (size_t)(nb * 128 + w * 32 + (lane >> 2)) * K + (lane & 3) * 8;
  bf16_t* Asw = As + (w * 32) * 32;
  bf16_t* Bsw = Bs + (w * 32) * 32;

  const int mrow0 = (w >> 1) * 64, ncol0 = (w & 1) * 64;

  for (int k0 = 0; k0 < K; k0 += 32) {
    gload16(Ag + k0, Asw);
    gload16(Ag + 16 * K + k0, Asw + 16 * 32);
    gload16(Bg + k0, Bsw);
    gload16(Bg + 16 * K + k0, Bsw + 16 * 32);
    asm volatile("s_waitcnt vmcnt(0)" ::: "memory");
    __syncthreads();

    bf16x8 av[4], bv[4];
#pragma unroll
    for (int mi = 0; mi < 4; ++mi)
      av[mi] = *reinterpret_cast<const bf16x8*>(As + (mrow0 + mi * 16 + r) * 32 + g * 8);
#pragma unroll
    for (int ni = 0; ni < 4; ++ni)
      bv[ni] = *reinterpret_cast<const bf16x8*>(Bs + (ncol0 + ni * 16 + r) * 32 + g * 8);
#pragma unroll
    for (int mi = 0; mi < 4; ++mi)
#pragma unroll
      for (int ni = 0; ni < 4; ++ni)
        acc[mi][ni] = __builtin_amdgcn_mfma_f32_16x16x32_bf16(av[mi], bv[ni], acc[mi][ni], 0, 0, 0);
    __syncthreads();
  }

  const int row0 = mb * 128 + mrow0;
  const int matk = nb >> 3;
  const int col0 = (nb & 7) * 128 + ncol0;
#pragma unroll
  for (int mi = 0; mi < 4; ++mi)
#pragma unroll
    for (int ni = 0; ni < 4; ++ni)
#pragma unroll
      for (int rr = 0; rr < 4; ++rr) {
        int row = row0 + mi * 16 + g * 4 + rr;
        int col = col0 + ni * 16 + r;
        int h = col >> 6, dd = col & 63;
        int s = row & 1023;
        size_t bh_ = (size_t)(row >> 10) * 16 + h;
        float v = acc[mi][ni][rr];
        if (matk == 0) {
          v *= aux[col] * 0.125f;  // mixing[h,dd] flat == col; fold 1/sqrt(64)
          o0[(bh_ * 1024 + s) * 64 + dd] = (bf16_t)v;
        } else if (matk == 1) {
          // K'[t][half][g][r][j]: t=s>>4, half=dd>>5, g=(dd>>3)&3, r=s&15, j=dd&7
          o1[bh_ * 65536 + (size_t)(s >> 4) * 1024 + (dd >> 5) * 512 +
             ((dd >> 3) & 3) * 128 + (s & 15) * 8 + (dd & 7)] = (bf16_t)v;
        } else {
          // V'[kbl][gk][d][j]: kbl=s>>5, gk=(s>>3)&3, d=dd, j=s&7
          o2[bh_ * 65536 + (size_t)(s >> 5) * 2048 + ((s >> 3) & 3) * 512 +
             dd * 8 + (s & 7)] = (bf16_t)v;
        }
      }
}

// ---------------- 64x128-tile dense GEMM, K=1024: out = A@Wd^T + bd (fp32, NT) ----------------
__global__ __launch_bounds__(256) void k_gemm_dense(const bf16_t* __restrict__ A,
                                                    const bf16_t* __restrict__ BT,
                                                    const float* __restrict__ bd,
                                                    float* __restrict__ of) {
  constexpr int K = 1024;
  const int tid = threadIdx.x;
  const int w = tid >> 6, lane = tid & 63;
  const int r = lane & 15, g = lane >> 4;
  const int swz = (blockIdx.x & 7) * 64 + (blockIdx.x >> 3);  // XCD-contiguous
  const int nb = swz & 7;
  const int mb = swz >> 3;

  __shared__ bf16_t As[64 * 32];
  __shared__ bf16_t Bs[128 * 32];

  f32x4 acc[2][4] = {};

  const bf16_t* Ag = A + (size_t)(mb * 64 + w * 16 + (lane >> 2)) * K + (lane & 3) * 8;
  const bf16_t* Bg = BT + (size_t)(nb * 128 + w * 32 + (lane >> 2)) * K + (lane & 3) * 8;
  bf16_t* Asw = As + (w * 16) * 32;
  bf16_t* Bsw = Bs + (w * 32) * 32;

  const int wr = w >> 1, wc = w & 1;
  const int mrow0 = wr * 32, ncol0 = wc * 64;

  for (int k0 = 0; k0 < K; k0 += 32) {
    gload16(Ag + k0, Asw);
    gload16(Bg + k0, Bsw);
    gload16(Bg + 16 * K + k0, Bsw + 16 * 32);
    asm volatile("s_waitcnt vmcnt(0)" ::: "memory");
    __syncthreads();

    bf16x8 av[2], bv[4];
#pragma unroll
    for (int mi = 0; mi < 2; ++mi)
      av[mi] = *reinterpret_cast<const bf16x8*>(As + (mrow0 + mi * 16 + r) * 32 + g * 8);
#pragma unroll
    for (int ni = 0; ni < 4; ++ni)
      bv[ni] = *reinterpret_cast<const bf16x8*>(Bs + (ncol0 + ni * 16 + r) * 32 + g * 8);
#pragma unroll
    for (int mi = 0; mi < 2; ++mi)
#pragma unroll
      for (int ni = 0; ni < 4; ++ni)
        acc[mi][ni] = __builtin_amdgcn_mfma_f32_16x16x32_bf16(av[mi], bv[ni], acc[mi][ni], 0, 0, 0);
    __syncthreads();
  }

  const int row0 = mb * 64 + mrow0, col0 = nb * 128 + ncol0;
#pragma unroll
  for (int mi = 0; mi < 2; ++mi)
#pragma unroll
    for (int ni = 0; ni < 4; ++ni)
#pragma unroll
      for (int rr = 0; rr < 4; ++rr) {
        int row = row0 + mi * 16 + g * 4 + rr;
        int col = col0 + ni * 16 + r;
        __builtin_nontemporal_store(acc[mi][ni][rr] + bd[col], of + (size_t)row * 1024 + col);
      }
}

// ---------------- fused attn v8: R9 structure + line-coalesced K'/V' loads ----------------
// block: one (b,h), 32 q rows; 4 waves; wave w owns keys [w*256,+256).
// Swapped QK^T: lane(r,g) holds keys T*16+g*4+{0..3} for q = qh*16 + r.
// K'/V' permuted layouts make every frag load an 8-line (vs 16) transaction --
// attacks the per-CU line-fill concurrency wall (R2-R11 invariant ~130us, all pipes idle).
// ALL acc indices compile-time (rule #20). P store LAST (no barrier after global stores).
__global__ __launch_bounds__(256, 2) void k_attn_fused(const bf16_t* __restrict__ Qm,
                                                       const bf16_t* __restrict__ Kp,
                                                       const bf16_t* __restrict__ Vp,
                                                       const float* __restrict__ cbm,
                                                       float* __restrict__ P,
                                                       bf16_t* __restrict__ aout) {
  const int tid = threadIdx.x;
  const int w = tid >> 6, lane = tid & 63;
  const int r = lane & 15, g = lane >> 4;
  const int swz = (blockIdx.x & 7) * 256 + (blockIdx.x >> 3);  // XCD-contiguous (b,h) groups
  const int qt = swz & 31;
  const int bh = swz >> 5;
  const int b = bh >> 4, h = bh & 15;
  const int q0 = qt * 32;

  constexpr int PSTR = 1032;  // row stride 2064B = 516 dwords (516%32=4 -> 2-way, free)
  __shared__ float red[2][32][4];
  __shared__ bf16_t Plds[32 * PSTR];  // 64.5 KB

  // Q frags (B-operand), 2 q-subtiles: q = q0 + qh*16 + r
  const bf16_t* qb = Qm + ((size_t)bh * 1024 + q0) * 64;
  bf16x8 bq00 = *reinterpret_cast<const bf16x8*>(qb + r * 64 + g * 8);
  bf16x8 bq01 = *reinterpret_cast<const bf16x8*>(qb + r * 64 + 32 + g * 8);
  bf16x8 bq10 = *reinterpret_cast<const bf16x8*>(qb + (16 + r) * 64 + g * 8);
  bf16x8 bq11 = *reinterpret_cast<const bf16x8*>(qb + (16 + r) * 64 + 32 + g * 8);

  // phase 1: S^T tiles. A-frag from K' (key tile T = w*16 + t): dense 1KB window per load.
  const bf16_t* kp = Kp + (size_t)bh * 65536 + w * 16384 + g * 128 + r * 8;
  f32x4 acc[16][2];
#pragma unroll
  for (int t = 0; t < 16; ++t) {
    bf16x8 a0 = *reinterpret_cast<const bf16x8*>(kp + t * 1024);
    bf16x8 a1 = *reinterpret_cast<const bf16x8*>(kp + t * 1024 + 512);
    f32x4 c0 = {0.f, 0.f, 0.f, 0.f};
    c0 = __builtin_amdgcn_mfma_f32_16x16x32_bf16(a0, bq00, c0, 0, 0, 0);
    c0 = __builtin_amdgcn_mfma_f32_16x16x32_bf16(a1, bq01, c0, 0, 0, 0);
    acc[t][0] = c0;
    f32x4 c1 = {0.f, 0.f, 0.f, 0.f};
    c1 = __builtin_amdgcn_mfma_f32_16x16x32_bf16(a0, bq10, c1, 0, 0, 0);
    c1 = __builtin_amdgcn_mfma_f32_16x16x32_bf16(a1, bq11, c1, 0, 0, 0);
    acc[t][1] = c1;
  }

  // bias+mask add (same per qh), per-lane max over this wave's 256 keys
  const float* cv = cbm + (size_t)bh * 1024 + w * 256;
  float mx[2] = {-1e30f, -1e30f};
#pragma unroll
  for (int t = 0; t < 16; ++t) {
    f32x4 c = *reinterpret_cast<const f32x4*>(cv + t * 16 + g * 4);
#pragma unroll
    for (int qh = 0; qh < 2; ++qh) {
      acc[t][qh] += c;
#pragma unroll
      for (int rr = 0; rr < 4; ++rr) mx[qh] = fmaxf(mx[qh], acc[t][qh][rr]);
    }
  }
#pragma unroll
  for (int qh = 0; qh < 2; ++qh) {
    mx[qh] = fmaxf(mx[qh], __shfl_xor(mx[qh], 16));
    mx[qh] = fmaxf(mx[qh], __shfl_xor(mx[qh], 32));
  }
  if (lane < 16) { red[0][r][w] = mx[0]; red[0][16 + r][w] = mx[1]; }
  __syncthreads();
  float m[2], sum[2] = {0.f, 0.f};
#pragma unroll
  for (int qh = 0; qh < 2; ++qh)
    m[qh] = fmaxf(fmaxf(red[0][qh * 16 + r][0], red[0][qh * 16 + r][1]),
                  fmaxf(red[0][qh * 16 + r][2], red[0][qh * 16 + r][3]));
#pragma unroll
  for (int t = 0; t < 16; ++t)
#pragma unroll
    for (int qh = 0; qh < 2; ++qh)
#pragma unroll
      for (int rr = 0; rr < 4; ++rr) {
        float p = __expf(acc[t][qh][rr] - m[qh]);
        acc[t][qh][rr] = p;
        sum[qh] += p;
      }
#pragma unroll
  for (int qh = 0; qh < 2; ++qh) {
    sum[qh] += __shfl_xor(sum[qh], 16);
    sum[qh] += __shfl_xor(sum[qh], 32);
  }
  if (lane < 16) { red[1][r][w] = sum[0]; red[1][16 + r][w] = sum[1]; }
  __syncthreads();
  float l[2];
#pragma unroll
  for (int qh = 0; qh < 2; ++qh)
    l[qh] = 1.f / (red[1][qh * 16 + r][0] + red[1][qh * 16 + r][1] +
                   red[1][qh * 16 + r][2] + red[1][qh * 16 + r][3]);

  // normalized P -> LDS (bf16, rows = q 0..31)
#pragma unroll
  for (int qh = 0; qh < 2; ++qh) {
    bf16_t* pl = Plds + (qh * 16 + r) * PSTR + w * 256;
#pragma unroll
    for (int t = 0; t < 16; ++t) {
      f32x4 pv = acc[t][qh] * l[qh];
      bf16x4 pk = { (bf16_t)pv[0], (bf16_t)pv[1], (bf16_t)pv[2], (bf16_t)pv[3] };
      *reinterpret_cast<bf16x4*>(pl + t * 16 + g * 4) = pk;
    }
  }
  __syncthreads();  // LDS-only waits: no global stores issued yet

  // phase 2: PV. wave w -> d-cols [w*16,+16). One V' load feeds both q-subtiles.
  const int dc = w * 16;
  const bf16_t* vp = Vp + (size_t)bh * 65536 + g * 512 + (dc + r) * 8;
  f32x4 oacc0 = {0.f, 0.f, 0.f, 0.f}, oacc1 = {0.f, 0.f, 0.f, 0.f};
#pragma unroll
  for (int kbl = 0; kbl < 32; ++kbl) {
    bf16x8 bv = *reinterpret_cast<const bf16x8*>(vp + kbl * 2048);
    bf16x8 av0 = *reinterpret_cast<const bf16x8*>(Plds + r * PSTR + kbl * 32 + g * 8);
    bf16x8 av1 = *reinterpret_cast<const bf16x8*>(Plds + (16 + r) * PSTR + kbl * 32 + g * 8);
    oacc0 = __builtin_amdgcn_mfma_f32_16x16x32_bf16(av0, bv, oacc0, 0, 0, 0);
    oacc1 = __builtin_amdgcn_mfma_f32_16x16x32_bf16(av1, bv, oacc1, 0, 0, 0);
  }
#pragma unroll
  for (int rr = 0; rr < 4; ++rr)
    aout[((size_t)b * 1024 + q0 + g * 4 + rr) * 1024 + h * 64 + dc + r] = (bf16_t)oacc0[rr];
#pragma unroll
  for (int rr = 0; rr < 4; ++rr)
    aout[((size_t)b * 1024 + q0 + 16 + g * 4 + rr) * 1024 + h * 64 + dc + r] = (bf16_t)oacc1[rr];

  // phase 3 (LAST): P fp32 coalesced NT store from Plds. Wave w owns rows [w*8,+8).
  {
    float* pg = P + ((size_t)bh * 1024 + q0) * 1024;
#pragma unroll
    for (int j = 0; j < 8; ++j) {
      const int row = w * 8 + j;
#pragma unroll
      for (int half = 0; half < 2; ++half) {
        const int col = half * 512 + lane * 8;
        bf16x8 v = *reinterpret_cast<const bf16x8*>(Plds + row * PSTR + col);
        f32x4 lo = { (float)v[0], (float)v[1], (float)v[2], (float)v[3] };
        f32x4 hi = { (float)v[4], (float)v[5], (float)v[6], (float)v[7] };
        float* dst = pg + (size_t)row * 1024 + col;
        __builtin_nontemporal_store(lo, reinterpret_cast<f32x4*>(dst));
        __builtin_nontemporal_store(hi, reinterpret_cast<f32x4*>(dst + 4));
      }
    }
  }
}

extern "C" void kernel_launch(void* const* d_in, const int* in_sizes, int n_in,
                              void* d_out, int out_size, void* d_ws, size_t ws_size,
                              hipStream_t stream) {
  const float* x      = (const float*)d_in[0];
  const float* mask   = (const float*)d_in[1];
  const float* Wq     = (const float*)d_in[2];
  const float* Wk     = (const float*)d_in[3];
  const float* Wv     = (const float*)d_in[4];
  const float* Wb     = (const float*)d_in[5];
  const float* mixing = (const float*)d_in[6];
  const float* Wd     = (const float*)d_in[7];
  const float* bd     = (const float*)d_in[8];

  char* ws = (char*)d_ws;
  bf16_t* xb   = (bf16_t*)(ws + 0);         //  8,388,608
  bf16_t* WqT  = (bf16_t*)(ws + 8388608);   //  2,097,152  } contiguous: one
  bf16_t* WkT  = (bf16_t*)(ws + 10485760);  //  2,097,152  } N=3072 B^T for
  bf16_t* WvT  = (bf16_t*)(ws + 12582912);  //  2,097,152  } fused QKV GEMM
  bf16_t* WdT  = (bf16_t*)(ws + 14680064);  //  2,097,152
  bf16_t* Qm   = (bf16_t*)(ws + 16777216);  //  8,388,608  [b,h,s,d] * mixing/8
  bf16_t* Kp   = (bf16_t*)(ws + 25165824);  //  8,388,608  K' permuted
  bf16_t* Vp   = (bf16_t*)(ws + 33554432);  //  8,388,608  V' permuted
  bf16_t* aout = (bf16_t*)(ws + 41943040);  //  8,388,608  [b,s,(h,hd)]
  float*  cbm  = (float*)(ws + 50331648);   //    262,144  [b,h,s] bias+mask
  if (ws_size < 50593792) return;

  float* outO = (float*)d_out;        // attn_output [4,1024,1024]
  float* outP = outO + 4194304;       // attn_weights [4,16,1024,1024]

  k_prep<<<4096, 256, 0, stream>>>(x, Wb, mask, xb, cbm);
  k_transpose_cvt4<<<dim3(1024, 4), 256, 0, stream>>>(Wq, Wk, Wv, Wd, WqT, WkT, WvT, WdT);
  k_gemm_qkv<<<768, 256, 0, stream>>>(xb, WqT, mixing, Qm, Kp, Vp);
  k_attn_fused<<<2048, 256, 0, stream>>>(Qm, Kp, Vp, cbm, outP, aout);
  k_gemm_dense<<<512, 256, 0, stream>>>(aout, WdT, bd, outO);
}

// Round 13
// 189.094 us; speedup vs baseline: 1.2571x; 1.0677x over previous
//
#include <hip/hip_runtime.h>

typedef __bf16 bf16_t;
typedef __bf16 bf16x4 __attribute__((ext_vector_type(4)));
typedef __bf16 bf16x8 __attribute__((ext_vector_type(8)));
typedef float  f32x4  __attribute__((ext_vector_type(4)));

// B=4, S=1024, D=1024, H=16, HD=64
// MFMA 16x16x32 bf16 layouts (m89/m91):
//   A-frag: row = lane&15, k = (lane>>4)*8 + j
//   B-frag: col = lane&15, k = (lane>>4)*8 + j  (from B^T rows)
//   C/D:    col = lane&15, row = (lane>>4)*4 + reg
//
// Attn-friendly permuted layouts (R12/R13): minimize cache-line touches per frag load.
//   Q'/K'[bh][t=row>>4][half=d>>5][g=(d>>3)&3][r=row&15][j=d&7]
//     -> frag load = 64 lanes reading one dense 1KB window (8 lines, was 16)
//   V'[bh][kbl=k>>5][gk=(k>>3)&3][d][j=k&7]
//     -> bv load = 4 aligned 256B chunks (8 lines, was 16)
// R13: attn global stores are REGULAR (L2-buffered), not nontemporal -- NT bypasses L2
// and the observed attn write BW (2.1-2.8 TB/s) was far below the fills' 6.9 TB/s.

__device__ __forceinline__ void gload16(const bf16_t* g, bf16_t* l) {
  __builtin_amdgcn_global_load_lds((const __attribute__((address_space(1))) void*)g,
                                   (__attribute__((address_space(3))) void*)l, 16, 0, 0);
}

// ---------------- fused prep: x fp32->bf16 + content bias + mask (one x read) ----------------
__global__ __launch_bounds__(256) void k_prep(const float* __restrict__ x,
                                              const float* __restrict__ Wb,
                                              const float* __restrict__ mask,
                                              bf16_t* __restrict__ xb,
                                              float* __restrict__ cbm) {
  const int row = blockIdx.x;
  const int t = threadIdx.x;
  __shared__ float xrow[1024];
  __shared__ float ps[16][17];

  const float4 v = *reinterpret_cast<const float4*>(x + (size_t)row * 1024 + t * 4);
  *reinterpret_cast<float4*>(xrow + t * 4) = v;
  bf16x4 o = { (bf16_t)v.x, (bf16_t)v.y, (bf16_t)v.z, (bf16_t)v.w };
  *reinterpret_cast<bf16x4*>(xb + (size_t)row * 1024 + t * 4) = o;
  __syncthreads();

  const int h = t & 15, part = t >> 4;
  const float* wb = Wb + (size_t)part * 64 * 16 + h;
  float s = 0.f;
#pragma unroll 8
  for (int i = 0; i < 64; ++i) s += xrow[part * 64 + i] * wb[i * 16];
  ps[part][h] = s;
  __syncthreads();
  if (t < 16) {
    float vv = 0.f;
#pragma unroll
    for (int p = 0; p < 16; ++p) vv += ps[p][t];
    cbm[((size_t)(row >> 10) * 16 + t) * 1024 + (row & 1023)] = vv + mask[row];
  }
}

// ---------------- batched transpose + cvt: WT[n][k] = W[k][n], 4x 1024x1024 ----------------
__global__ __launch_bounds__(256) void k_transpose_cvt4(
    const float* __restrict__ W0, const float* __restrict__ W1,
    const float* __restrict__ W2, const float* __restrict__ W3,
    bf16_t* __restrict__ T0, bf16_t* __restrict__ T1,
    bf16_t* __restrict__ T2, bf16_t* __restrict__ T3) {
  const float* W; bf16_t* WT;
  switch (blockIdx.y) {
    case 0: W = W0; WT = T0; break;
    case 1: W = W1; WT = T1; break;
    case 2: W = W2; WT = T2; break;
    default: W = W3; WT = T3; break;
  }
  __shared__ float t[32][33];
  int bx = blockIdx.x & 31, by = blockIdx.x >> 5;
  int lx = threadIdx.x & 31, ly = threadIdx.x >> 5;
#pragma unroll
  for (int i = 0; i < 32; i += 8)
    t[ly + i][lx] = W[(size_t)(by * 32 + ly + i) * 1024 + bx * 32 + lx];
  __syncthreads();
#pragma unroll
  for (int i = 0; i < 32; i += 8)
    WT[(size_t)(bx * 32 + ly + i) * 1024 + by * 32 + lx] = (bf16_t)t[lx][ly + i];
}

// ---------------- 128x128-tile bf16 GEMM, K=1024 (fused QKV, N=3072) ----------------
// nb 0..7 -> Q' permuted (*mixing/8); nb 8..15 -> K' permuted; nb 16..23 -> V' permuted.
__global__ __launch_bounds__(256) void k_gemm_qkv(const bf16_t* __restrict__ A,
                                                  const bf16_t* __restrict__ BT,
                                                  const float* __restrict__ aux,
                                                  bf16_t* __restrict__ o0,
                                                  bf16_t* __restrict__ o1,
                                                  bf16_t* __restrict__ o2) {
  constexpr int K = 1024;
  const int tid = threadIdx.x;
  const int w = tid >> 6, lane = tid & 63;
  const int r = lane & 15, g = lane >> 4;
  const int swz = (blockIdx.x & 7) * 96 + (blockIdx.x >> 3);  // XCD-contiguous
  const int nb = swz % 24;
  const int mb = swz / 24;

  __shared__ bf16_t As[128 * 32];
  __shared__ bf16_t Bs[128 * 32];

  f32x4 acc[4][4] = {};

  const bf16_t* Ag = A + (size_t)(mb * 128 + w * 32 + (lane >> 2)) * K + (lane & 3) * 8;
  const bf16_t* Bg = BT + (size_t)(nb * 128 + w * 32 + (lane >> 2)) * K + (lane & 3) * 8;
  bf16_t* Asw = As + (w * 32) * 32;
  bf16_t* Bsw = Bs + (w * 32) * 32;

  const int mrow0 = (w >> 1) * 64, ncol0 = (w & 1) * 64;

  for (int k0 = 0; k0 < K; k0 += 32) {
    gload16(Ag + k0, Asw);
    gload16(Ag + 16 * K + k0, Asw + 16 * 32);
    gload16(Bg + k0, Bsw);
    gload16(Bg + 16 * K + k0, Bsw + 16 * 32);
    asm volatile("s_waitcnt vmcnt(0)" ::: "memory");
    __syncthreads();

    bf16x8 av[4], bv[4];
#pragma unroll
    for (int mi = 0; mi < 4; ++mi)
      av[mi] = *reinterpret_cast<const bf16x8*>(As + (mrow0 + mi * 16 + r) * 32 + g * 8);
#pragma unroll
    for (int ni = 0; ni < 4; ++ni)
      bv[ni] = *reinterpret_cast<const bf16x8*>(Bs + (ncol0 + ni * 16 + r) * 32 + g * 8);
#pragma unroll
    for (int mi = 0; mi < 4; ++mi)
#pragma unroll
      for (int ni = 0; ni < 4; ++ni)
        acc[mi][ni] = __builtin_amdgcn_mfma_f32_16x16x32_bf16(av[mi], bv[ni], acc[mi][ni], 0, 0, 0);
    __syncthreads();
  }

  const int row0 = mb * 128 + mrow0;
  const int matk = nb >> 3;
  const int col0 = (nb & 7) * 128 + ncol0;
#pragma unroll
  for (int mi = 0; mi < 4; ++mi)
#pragma unroll
    for (int ni = 0; ni < 4; ++ni)
#pragma unroll
      for (int rr = 0; rr < 4; ++rr) {
        int row = row0 + mi * 16 + g * 4 + rr;
        int col = col0 + ni * 16 + r;
        int h = col >> 6, dd = col & 63;
        int s = row & 1023;
        size_t bh_ = (size_t)(row >> 10) * 16 + h;
        float v = acc[mi][ni][rr];
        if (matk == 0) {
          v *= aux[col] * 0.125f;  // mixing[h,dd] flat == col; fold 1/sqrt(64)
          // Q'[t][half][g][r][j] (same permutation as K')
          o0[bh_ * 65536 + (size_t)(s >> 4) * 1024 + (dd >> 5) * 512 +
             ((dd >> 3) & 3) * 128 + (s & 15) * 8 + (dd & 7)] = (bf16_t)v;
        } else if (matk == 1) {
          // K'[t][half][g][r][j]: t=s>>4, half=dd>>5, g=(dd>>3)&3, r=s&15, j=dd&7
          o1[bh_ * 65536 + (size_t)(s >> 4) * 1024 + (dd >> 5) * 512 +
             ((dd >> 3) & 3) * 128 + (s & 15) * 8 + (dd & 7)] = (bf16_t)v;
        } else {
          // V'[kbl][gk][d][j]: kbl=s>>5, gk=(s>>3)&3, d=dd, j=s&7
          o2[bh_ * 65536 + (size_t)(s >> 5) * 2048 + ((s >> 3) & 3) * 512 +
             dd * 8 + (s & 7)] = (bf16_t)v;
        }
      }
}

// ---------------- 64x128-tile dense GEMM, K=1024: out = A@Wd^T + bd (fp32, NT) ----------------
__global__ __launch_bounds__(256) void k_gemm_dense(const bf16_t* __restrict__ A,
                                                    const bf16_t* __restrict__ BT,
                                                    const float* __restrict__ bd,
                                                    float* __restrict__ of) {
  constexpr int K = 1024;
  const int tid = threadIdx.x;
  const int w = tid >> 6, lane = tid & 63;
  const int r = lane & 15, g = lane >> 4;
  const int swz = (blockIdx.x & 7) * 64 + (blockIdx.x >> 3);  // XCD-contiguous
  const int nb = swz & 7;
  const int mb = swz >> 3;

  __shared__ bf16_t As[64 * 32];
  __shared__ bf16_t Bs[128 * 32];

  f32x4 acc[2][4] = {};

  const bf16_t* Ag = A + (size_t)(mb * 64 + w * 16 + (lane >> 2)) * K + (lane & 3) * 8;
  const bf16_t* Bg = BT + (size_t)(nb * 128 + w * 32 + (lane >> 2)) * K + (lane & 3) * 8;
  bf16_t* Asw = As + (w * 16) * 32;
  bf16_t* Bsw = Bs + (w * 32) * 32;

  const int wr = w >> 1, wc = w & 1;
  const int mrow0 = wr * 32, ncol0 = wc * 64;

  for (int k0 = 0; k0 < K; k0 += 32) {
    gload16(Ag + k0, Asw);
    gload16(Bg + k0, Bsw);
    gload16(Bg + 16 * K + k0, Bsw + 16 * 32);
    asm volatile("s_waitcnt vmcnt(0)" ::: "memory");
    __syncthreads();

    bf16x8 av[2], bv[4];
#pragma unroll
    for (int mi = 0; mi < 2; ++mi)
      av[mi] = *reinterpret_cast<const bf16x8*>(As + (mrow0 + mi * 16 + r) * 32 + g * 8);
#pragma unroll
    for (int ni = 0; ni < 4; ++ni)
      bv[ni] = *reinterpret_cast<const bf16x8*>(Bs + (ncol0 + ni * 16 + r) * 32 + g * 8);
#pragma unroll
    for (int mi = 0; mi < 2; ++mi)
#pragma unroll
      for (int ni = 0; ni < 4; ++ni)
        acc[mi][ni] = __builtin_amdgcn_mfma_f32_16x16x32_bf16(av[mi], bv[ni], acc[mi][ni], 0, 0, 0);
    __syncthreads();
  }

  const int row0 = mb * 64 + mrow0, col0 = nb * 128 + ncol0;
#pragma unroll
  for (int mi = 0; mi < 2; ++mi)
#pragma unroll
    for (int ni = 0; ni < 4; ++ni)
#pragma unroll
      for (int rr = 0; rr < 4; ++rr) {
        int row = row0 + mi * 16 + g * 4 + rr;
        int col = col0 + ni * 16 + r;
        __builtin_nontemporal_store(acc[mi][ni][rr] + bd[col], of + (size_t)row * 1024 + col);
      }
}

// ---------------- fused attn v9: dense Q'/K'/V' loads + REGULAR (L2) stores ----------------
// block: one (b,h), 32 q rows; 4 waves; wave w owns keys [w*256,+256).
// Swapped QK^T: lane(r,g) holds keys T*16+g*4+{0..3} for q = qh*16 + r.
// All frag loads are dense 8-line transactions. P/aout stores are regular (L2-buffered):
// NT bypasses L2 and capped attn write BW at ~2-3 TB/s vs fills' 6.9 TB/s (R13 hypothesis).
// ALL acc indices compile-time (rule #20). Stores still last (no barrier after them).
__global__ __launch_bounds__(256, 2) void k_attn_fused(const bf16_t* __restrict__ Qp,
                                                       const bf16_t* __restrict__ Kp,
                                                       const bf16_t* __restrict__ Vp,
                                                       const float* __restrict__ cbm,
                                                       float* __restrict__ P,
                                                       bf16_t* __restrict__ aout) {
  const int tid = threadIdx.x;
  const int w = tid >> 6, lane = tid & 63;
  const int r = lane & 15, g = lane >> 4;
  const int swz = (blockIdx.x & 7) * 256 + (blockIdx.x >> 3);  // XCD-contiguous (b,h) groups
  const int qt = swz & 31;
  const int bh = swz >> 5;
  const int b = bh >> 4, h = bh & 15;
  const int q0 = qt * 32;

  constexpr int PSTR = 1032;  // row stride 2064B = 516 dwords (516%32=4 -> 2-way, free)
  __shared__ float red[2][32][4];
  __shared__ bf16_t Plds[32 * PSTR];  // 64.5 KB

  // Q' frags (B-operand), 2 q-subtiles: dense 1KB windows
  const bf16_t* qp = Qp + (size_t)bh * 65536 + (size_t)(qt * 2) * 1024 + g * 128 + r * 8;
  bf16x8 bq00 = *reinterpret_cast<const bf16x8*>(qp);
  bf16x8 bq01 = *reinterpret_cast<const bf16x8*>(qp + 512);
  bf16x8 bq10 = *reinterpret_cast<const bf16x8*>(qp + 1024);
  bf16x8 bq11 = *reinterpret_cast<const bf16x8*>(qp + 1536);

  // phase 1: S^T tiles. A-frag from K' (key tile T = w*16 + t): dense 1KB window per load.
  const bf16_t* kp = Kp + (size_t)bh * 65536 + w * 16384 + g * 128 + r * 8;
  f32x4 acc[16][2];
#pragma unroll
  for (int t = 0; t < 16; ++t) {
    bf16x8 a0 = *reinterpret_cast<const bf16x8*>(kp + t * 1024);
    bf16x8 a1 = *reinterpret_cast<const bf16x8*>(kp + t * 1024 + 512);
    f32x4 c0 = {0.f, 0.f, 0.f, 0.f};
    c0 = __builtin_amdgcn_mfma_f32_16x16x32_bf16(a0, bq00, c0, 0, 0, 0);
    c0 = __builtin_amdgcn_mfma_f32_16x16x32_bf16(a1, bq01, c0, 0, 0, 0);
    acc[t][0] = c0;
    f32x4 c1 = {0.f, 0.f, 0.f, 0.f};
    c1 = __builtin_amdgcn_mfma_f32_16x16x32_bf16(a0, bq10, c1, 0, 0, 0);
    c1 = __builtin_amdgcn_mfma_f32_16x16x32_bf16(a1, bq11, c1, 0, 0, 0);
    acc[t][1] = c1;
  }

  // bias+mask add (same per qh), per-lane max over this wave's 256 keys
  const float* cv = cbm + (size_t)bh * 1024 + w * 256;
  float mx[2] = {-1e30f, -1e30f};
#pragma unroll
  for (int t = 0; t < 16; ++t) {
    f32x4 c = *reinterpret_cast<const f32x4*>(cv + t * 16 + g * 4);
#pragma unroll
    for (int qh = 0; qh < 2; ++qh) {
      acc[t][qh] += c;
#pragma unroll
      for (int rr = 0; rr < 4; ++rr) mx[qh] = fmaxf(mx[qh], acc[t][qh][rr]);
    }
  }
#pragma unroll
  for (int qh = 0; qh < 2; ++qh) {
    mx[qh] = fmaxf(mx[qh], __shfl_xor(mx[qh], 16));
    mx[qh] = fmaxf(mx[qh], __shfl_xor(mx[qh], 32));
  }
  if (lane < 16) { red[0][r][w] = mx[0]; red[0][16 + r][w] = mx[1]; }
  __syncthreads();
  float m[2], sum[2] = {0.f, 0.f};
#pragma unroll
  for (int qh = 0; qh < 2; ++qh)
    m[qh] = fmaxf(fmaxf(red[0][qh * 16 + r][0], red[0][qh * 16 + r][1]),
                  fmaxf(red[0][qh * 16 + r][2], red[0][qh * 16 + r][3]));
#pragma unroll
  for (int t = 0; t < 16; ++t)
#pragma unroll
    for (int qh = 0; qh < 2; ++qh)
#pragma unroll
      for (int rr = 0; rr < 4; ++rr) {
        float p = __expf(acc[t][qh][rr] - m[qh]);
        acc[t][qh][rr] = p;
        sum[qh] += p;
      }
#pragma unroll
  for (int qh = 0; qh < 2; ++qh) {
    sum[qh] += __shfl_xor(sum[qh], 16);
    sum[qh] += __shfl_xor(sum[qh], 32);
  }
  if (lane < 16) { red[1][r][w] = sum[0]; red[1][16 + r][w] = sum[1]; }
  __syncthreads();
  float l[2];
#pragma unroll
  for (int qh = 0; qh < 2; ++qh)
    l[qh] = 1.f / (red[1][qh * 16 + r][0] + red[1][qh * 16 + r][1] +
                   red[1][qh * 16 + r][2] + red[1][qh * 16 + r][3]);

  // normalized P -> LDS (bf16, rows = q 0..31)
#pragma unroll
  for (int qh = 0; qh < 2; ++qh) {
    bf16_t* pl = Plds + (qh * 16 + r) * PSTR + w * 256;
#pragma unroll
    for (int t = 0; t < 16; ++t) {
      f32x4 pv = acc[t][qh] * l[qh];
      bf16x4 pk = { (bf16_t)pv[0], (bf16_t)pv[1], (bf16_t)pv[2], (bf16_t)pv[3] };
      *reinterpret_cast<bf16x4*>(pl + t * 16 + g * 4) = pk;
    }
  }
  __syncthreads();  // LDS-only waits: no global stores issued yet

  // phase 2: PV. wave w -> d-cols [w*16,+16). One V' load feeds both q-subtiles.
  const int dc = w * 16;
  const bf16_t* vp = Vp + (size_t)bh * 65536 + g * 512 + (dc + r) * 8;
  f32x4 oacc0 = {0.f, 0.f, 0.f, 0.f}, oacc1 = {0.f, 0.f, 0.f, 0.f};
#pragma unroll
  for (int kbl = 0; kbl < 32; ++kbl) {
    bf16x8 bv = *reinterpret_cast<const bf16x8*>(vp + kbl * 2048);
    bf16x8 av0 = *reinterpret_cast<const bf16x8*>(Plds + r * PSTR + kbl * 32 + g * 8);
    bf16x8 av1 = *reinterpret_cast<const bf16x8*>(Plds + (16 + r) * PSTR + kbl * 32 + g * 8);
    oacc0 = __builtin_amdgcn_mfma_f32_16x16x32_bf16(av0, bv, oacc0, 0, 0, 0);
    oacc1 = __builtin_amdgcn_mfma_f32_16x16x32_bf16(av1, bv, oacc1, 0, 0, 0);
  }
#pragma unroll
  for (int rr = 0; rr < 4; ++rr)
    aout[((size_t)b * 1024 + q0 + g * 4 + rr) * 1024 + h * 64 + dc + r] = (bf16_t)oacc0[rr];
#pragma unroll
  for (int rr = 0; rr < 4; ++rr)
    aout[((size_t)b * 1024 + q0 + 16 + g * 4 + rr) * 1024 + h * 64 + dc + r] = (bf16_t)oacc1[rr];

  // phase 3 (LAST): P fp32 coalesced REGULAR store from Plds. Wave w owns rows [w*8,+8).
  {
    float* pg = P + ((size_t)bh * 1024 + q0) * 1024;
#pragma unroll
    for (int j = 0; j < 8; ++j) {
      const int row = w * 8 + j;
#pragma unroll
      for (int half = 0; half < 2; ++half) {
        const int col = half * 512 + lane * 8;
        bf16x8 v = *reinterpret_cast<const bf16x8*>(Plds + row * PSTR + col);
        f32x4 lo = { (float)v[0], (float)v[1], (float)v[2], (float)v[3] };
        f32x4 hi = { (float)v[4], (float)v[5], (float)v[6], (float)v[7] };
        float* dst = pg + (size_t)row * 1024 + col;
        *reinterpret_cast<f32x4*>(dst) = lo;
        *reinterpret_cast<f32x4*>(dst + 4) = hi;
      }
    }
  }
}

extern "C" void kernel_launch(void* const* d_in, const int* in_sizes, int n_in,
                              void* d_out, int out_size, void* d_ws, size_t ws_size,
                              hipStream_t stream) {
  const float* x      = (const float*)d_in[0];
  const float* mask   = (const float*)d_in[1];
  const float* Wq     = (const float*)d_in[2];
  const float* Wk     = (const float*)d_in[3];
  const float* Wv     = (const float*)d_in[4];
  const float* Wb     = (const float*)d_in[5];
  const float* mixing = (const float*)d_in[6];
  const float* Wd     = (const float*)d_in[7];
  const float* bd     = (const float*)d_in[8];

  char* ws = (char*)d_ws;
  bf16_t* xb   = (bf16_t*)(ws + 0);         //  8,388,608
  bf16_t* WqT  = (bf16_t*)(ws + 8388608);   //  2,097,152  } contiguous: one
  bf16_t* WkT  = (bf16_t*)(ws + 10485760);  //  2,097,152  } N=3072 B^T for
  bf16_t* WvT  = (bf16_t*)(ws + 12582912);  //  2,097,152  } fused QKV GEMM
  bf16_t* WdT  = (bf16_t*)(ws + 14680064);  //  2,097,152
  bf16_t* Qp   = (bf16_t*)(ws + 16777216);  //  8,388,608  Q' permuted (* mixing/8)
  bf16_t* Kp   = (bf16_t*)(ws + 25165824);  //  8,388,608  K' permuted
  bf16_t* Vp   = (bf16_t*)(ws + 33554432);  //  8,388,608  V' permuted
  bf16_t* aout = (bf16_t*)(ws + 41943040);  //  8,388,608  [b,s,(h,hd)]
  float*  cbm  = (float*)(ws + 50331648);   //    262,144  [b,h,s] bias+mask
  if (ws_size < 50593792) return;

  float* outO = (float*)d_out;        // attn_output [4,1024,1024]
  float* outP = outO + 4194304;       // attn_weights [4,16,1024,1024]

  k_prep<<<4096, 256, 0, stream>>>(x, Wb, mask, xb, cbm);
  k_transpose_cvt4<<<dim3(1024, 4), 256, 0, stream>>>(Wq, Wk, Wv, Wd, WqT, WkT, WvT, WdT);
  k_gemm_qkv<<<768, 256, 0, stream>>>(xb, WqT, mixing, Qp, Kp, Vp);
  k_attn_fused<<<2048, 256, 0, stream>>>(Qp, Kp, Vp, cbm, outP, aout);
  k_gemm_dense<<<512, 256, 0, stream>>>(aout, WdT, bd, outO);
}